// Round 6
// baseline (138.060 us; speedup 1.0000x reference)
//
#include <hip/hip_runtime.h>

#define NH 16
#define HD 64
#define LSEQ 2048
#define BQ 128
#define BK 64
#define NQT (LSEQ / BQ)          // 16
#define RS (NH * HD)             // 1024 floats per token row
#define NTILE 4                  // kt = 2qt-1 .. 2qt+2: minimal band (edge queries get +-64)

#define KSTR 72                  // b64 stores ~free; b128 reads 2-way
#define VSTR 74                  // scatter b16 stores 2-way (bank step 20); b128 reads ~2-way
#define PSTR 72                  // b64 stores 2-way; b128 reads 2-way

typedef __bf16 bf16x8 __attribute__((ext_vector_type(8)));
typedef __bf16 bf16x4 __attribute__((ext_vector_type(4)));
typedef float f32x4 __attribute__((ext_vector_type(4)));

// exp(-8): fixed softmax shift folded into the mask multiplier; cancels in O/l.
#define EXP_NEG8 0.00033546262790251185f

__global__ __launch_bounds__(512, 4)   // 4 waves/SIMD -> VGPR cap 128, 2 blocks/CU
void attn_kernel(const float* __restrict__ Q,
                 const float* __restrict__ K,
                 const float* __restrict__ V,
                 const int* __restrict__ Mk,
                 float* __restrict__ Out)
{
    __shared__ alignas(16) __bf16 sK[2][BK][KSTR];    // 18432 B
    __shared__ alignas(16) __bf16 sVt[2][HD][VSTR];   // 18944 B, V transposed [d][k]
    __shared__ alignas(16) __bf16 sPT[8][16][PSTR];   // 18432 B, P^T per wave: [q][k]

    const int tid  = threadIdx.x;
    const int wave = tid >> 6;
    const int lane = tid & 63;
    const int ln   = lane & 15;
    const int quad = lane >> 4;

    const int qt = blockIdx.x & (NQT - 1);
    const int bh = blockIdx.x >> 4;
    const int b  = bh >> 4;
    const int h  = bh & 15;

    const int q0   = qt * BQ;
    const int qrow = q0 + wave * 16;

    const size_t bh_off = ((size_t)b * LSEQ) * RS + (size_t)h * HD;
    const float* gQ = Q + bh_off;
    const float* gK = K + bh_off;
    const float* gV = V + bh_off;
    const int*   gM = Mk + (size_t)b * LSEQ;
    float*       gO = Out + bh_off;

    // staging map: idx = tid + i*512 -> (row 0..63, 16B chunk 0..15)
    int srow[2], sc4[2];
#pragma unroll
    for (int i = 0; i < 2; ++i) { int idx = tid + i * 512; srow[i] = idx >> 4; sc4[i] = idx & 15; }

    int k0s[NTILE];
#pragma unroll
    for (int j = 0; j < NTILE; ++j) k0s[j] = ((2 * qt + 31 + j) & 31) * BK;

    // ---- all 4 tiles' masks, packed: bit (t*4+r) of mbits[j] <-> k = k0s[j]+t*16+quad*4+r
    unsigned mbits[NTILE];
#pragma unroll
    for (int j = 0; j < NTILE; ++j) {
        unsigned bits = 0;
#pragma unroll
        for (int t = 0; t < 4; ++t) {
            int4 m = *(const int4*)(gM + k0s[j] + t * 16 + quad * 4);
            bits |= (m.x ? 1u : 0u) << (t * 4 + 0);
            bits |= (m.y ? 1u : 0u) << (t * 4 + 1);
            bits |= (m.z ? 1u : 0u) << (t * 4 + 2);
            bits |= (m.w ? 1u : 0u) << (t * 4 + 3);
        }
        mbits[j] = bits;
    }

    // ---- Q fragments, pre-scaled by 1/sqrt(D); B-operand of S^T = K Q^T
    bf16x8 qfrag[2];
#pragma unroll
    for (int c = 0; c < 2; ++c) {
        const float* src = gQ + (size_t)(qrow + ln) * RS + c * 32 + quad * 8;
        float4 f0 = *(const float4*)(src);
        float4 f1 = *(const float4*)(src + 4);
        bf16x8 t;
        t[0] = (__bf16)(f0.x * 0.125f); t[1] = (__bf16)(f0.y * 0.125f);
        t[2] = (__bf16)(f0.z * 0.125f); t[3] = (__bf16)(f0.w * 0.125f);
        t[4] = (__bf16)(f1.x * 0.125f); t[5] = (__bf16)(f1.y * 0.125f);
        t[6] = (__bf16)(f1.z * 0.125f); t[7] = (__bf16)(f1.w * 0.125f);
        qfrag[c] = t;
    }

    f32x4 o_acc[4];   // O^T C-layout: lane holds O[q=qrow+ln][d=nt*16+quad*4+r]
#pragma unroll
    for (int i = 0; i < 4; ++i) o_acc[i] = f32x4{0.f, 0.f, 0.f, 0.f};
    float l_sum = 0.f;

    // ---- depth-2 register prefetch queue: slot = tile & 1 ----
    float4 kq[2][2], vq[2][2];
#pragma unroll
    for (int s = 0; s < 2; ++s)
#pragma unroll
        for (int i = 0; i < 2; ++i) {
            kq[s][i] = *(const float4*)(gK + (size_t)(k0s[s] + srow[i]) * RS + sc4[i] * 4);
            vq[s][i] = *(const float4*)(gV + (size_t)(k0s[s] + srow[i]) * RS + sc4[i] * 4);
        }

#pragma unroll
    for (int j = 0; j < NTILE; ++j) {
        const int bb = j & 1;
        const int k0 = k0s[j];

        // ---- store queued tile j (slot bb) into LDS buffer bb ----
#pragma unroll
        for (int i = 0; i < 2; ++i) {
            float4 f = kq[bb][i];
            bf16x4 kk;
            kk[0] = (__bf16)f.x; kk[1] = (__bf16)f.y;
            kk[2] = (__bf16)f.z; kk[3] = (__bf16)f.w;
            *(bf16x4*)&sK[bb][srow[i]][sc4[i] * 4] = kk;
            float4 g = vq[bb][i];
            sVt[bb][sc4[i] * 4 + 0][srow[i]] = (__bf16)g.x;
            sVt[bb][sc4[i] * 4 + 1][srow[i]] = (__bf16)g.y;
            sVt[bb][sc4[i] * 4 + 2][srow[i]] = (__bf16)g.z;
            sVt[bb][sc4[i] * 4 + 3][srow[i]] = (__bf16)g.w;
        }

        // ---- refill slot bb with tile j+2 (arrives ~2 compute phases later) ----
        if (j + 2 < NTILE) {
            const int k0n = k0s[j + 2];
#pragma unroll
            for (int i = 0; i < 2; ++i) {
                kq[bb][i] = *(const float4*)(gK + (size_t)(k0n + srow[i]) * RS + sc4[i] * 4);
                vq[bb][i] = *(const float4*)(gV + (size_t)(k0n + srow[i]) * RS + sc4[i] * 4);
            }
        }
        __syncthreads();   // single barrier per tile (double-buffered K/V)

        // ---- S^T = K Q^T: C-layout row = k-sub = quad*4+r, col = q = ln ----
        f32x4 st[4];
#pragma unroll
        for (int t = 0; t < 4; ++t) {
            f32x4 acc = f32x4{0.f, 0.f, 0.f, 0.f};
#pragma unroll
            for (int ch = 0; ch < 2; ++ch) {
                bf16x8 kf = *(const bf16x8*)&sK[bb][t * 16 + ln][ch * 32 + quad * 8];
                acc = __builtin_amdgcn_mfma_f32_16x16x32_bf16(kf, qfrag[ch], acc, 0, 0, 0);
            }
            st[t] = acc;
        }

        // ---- fixed-shift softmax; P^T stored k-contiguous (one b64 per block) ----
        const int qg = qrow + ln;
#pragma unroll
        for (int t = 0; t < 4; ++t) {
            bf16x4 pt;
#pragma unroll
            for (int r = 0; r < 4; ++r) {
                int kg = k0 + t * 16 + quad * 4 + r;
                int dd = qg - kg; dd = dd < 0 ? -dd : dd;
                int d2 = LSEQ - dd; dd = d2 < dd ? d2 : dd;
                float mf = ((mbits[j] >> (t * 4 + r)) & 1u) ? EXP_NEG8 : 0.f;
                float p = __expf(st[t][r] - (float)dd) * mf;
                l_sum += p;
                pt[r] = (__bf16)p;
            }
            *(bf16x4*)&sPT[wave][ln][t * 16 + quad * 4] = pt;
        }

        // ---- O^T += V^T P^T ----
#pragma unroll
        for (int ch = 0; ch < 2; ++ch) {
            bf16x8 pb = *(const bf16x8*)&sPT[wave][ln][ch * 32 + quad * 8];
#pragma unroll
            for (int nt = 0; nt < 4; ++nt) {
                bf16x8 vf = *(const bf16x8*)&sVt[bb][nt * 16 + ln][ch * 32 + quad * 8];
                o_acc[nt] = __builtin_amdgcn_mfma_f32_16x16x32_bf16(vf, pb, o_acc[nt], 0, 0, 0);
            }
        }
        // no trailing barrier: next iter writes the other K/V buffer; its barrier orders reuse.
    }

    // ---- epilogue: reduce l across quads (2 shuffles), nontemporal coalesced stores ----
    float l = l_sum;
    l += __shfl_xor(l, 16, 64);
    l += __shfl_xor(l, 32, 64);
    const float inv = 1.f / l;

    float* dst = gO + (size_t)(qrow + ln) * RS + quad * 4;
#pragma unroll
    for (int nt = 0; nt < 4; ++nt) {
        f32x4 ov;
        ov[0] = o_acc[nt][0] * inv;
        ov[1] = o_acc[nt][1] * inv;
        ov[2] = o_acc[nt][2] * inv;
        ov[3] = o_acc[nt][3] * inv;
        __builtin_nontemporal_store(ov, (f32x4*)(dst + nt * 16));
    }
}

extern "C" void kernel_launch(void* const* d_in, const int* in_sizes, int n_in,
                              void* d_out, int out_size, void* d_ws, size_t ws_size,
                              hipStream_t stream) {
    const float* Q  = (const float*)d_in[0];
    const float* K  = (const float*)d_in[1];
    const float* V  = (const float*)d_in[2];
    const int*   Mk = (const int*)d_in[3];
    float*       O  = (float*)d_out;

    dim3 grid(2 * NH * NQT);   // 512 blocks
    dim3 block(512);
    attn_kernel<<<grid, block, 0, stream>>>(Q, K, V, Mk, O);
}

// Round 7
// 120.764 us; speedup vs baseline: 1.1432x; 1.1432x over previous
//
#include <hip/hip_runtime.h>

#define NH 16
#define HD 64
#define LSEQ 2048
#define BQ 128
#define BK 64
#define NQT (LSEQ / BQ)          // 16
#define RS (NH * HD)             // 1024 floats per token row
#define NTILE 4                  // kt = 2qt-1 .. 2qt+2: minimal band (edge queries get +-64)

#define KSTR 72                  // b64 stores ~free; b128 reads 2-way
#define VSTR 74                  // scatter b16 stores 2-way (bank step 20); b128 reads ~2-way
#define PSTR 72                  // b64 stores 2-way; b128 reads 2-way

typedef __bf16 bf16x8 __attribute__((ext_vector_type(8)));
typedef __bf16 bf16x4 __attribute__((ext_vector_type(4)));
typedef float f32x4 __attribute__((ext_vector_type(4)));

// exp(-8): fixed softmax shift folded into the mask multiplier; cancels in O/l.
#define EXP_NEG8 0.00033546262790251185f

// waves_per_eu(4,4): pin exactly 4 waves/EU -> VGPR budget 128. R6 showed the
// allocator otherwise targets 8 waves/EU (64 VGPR) and SPILLS the prefetch
// queue to scratch (FETCH +30MB, WRITE +63MB, dur +50%).
__global__ void
__attribute__((amdgpu_flat_work_group_size(512, 512), amdgpu_waves_per_eu(4, 4)))
attn_kernel(const float* __restrict__ Q,
            const float* __restrict__ K,
            const float* __restrict__ V,
            const int* __restrict__ Mk,
            float* __restrict__ Out)
{
    __shared__ alignas(16) __bf16 sK[2][BK][KSTR];    // 18432 B
    __shared__ alignas(16) __bf16 sVt[2][HD][VSTR];   // 18944 B, V transposed [d][k]
    __shared__ alignas(16) __bf16 sPT[8][16][PSTR];   // 18432 B, P^T per wave: [q][k]

    const int tid  = threadIdx.x;
    const int wave = tid >> 6;
    const int lane = tid & 63;
    const int ln   = lane & 15;
    const int quad = lane >> 4;

    const int qt = blockIdx.x & (NQT - 1);
    const int bh = blockIdx.x >> 4;
    const int b  = bh >> 4;
    const int h  = bh & 15;

    const int q0   = qt * BQ;
    const int qrow = q0 + wave * 16;

    const size_t bh_off = ((size_t)b * LSEQ) * RS + (size_t)h * HD;
    const float* gQ = Q + bh_off;
    const float* gK = K + bh_off;
    const float* gV = V + bh_off;
    const int*   gM = Mk + (size_t)b * LSEQ;
    float*       gO = Out + bh_off;

    // staging map: idx = tid + i*512 -> (row 0..63, 16B chunk 0..15)
    int srow[2], sc4[2];
#pragma unroll
    for (int i = 0; i < 2; ++i) { int idx = tid + i * 512; srow[i] = idx >> 4; sc4[i] = idx & 15; }

    int k0s[NTILE];
#pragma unroll
    for (int j = 0; j < NTILE; ++j) k0s[j] = ((2 * qt + 31 + j) & 31) * BK;

    // ---- prefetch ALL tiles' K/V into registers up front: 16 float4 loads in
    // flight per thread (max MLP); tile j's vmcnt wait is covered by j compute phases.
    float4 kq[NTILE][2], vq[NTILE][2];
#pragma unroll
    for (int j = 0; j < NTILE; ++j)
#pragma unroll
        for (int i = 0; i < 2; ++i) {
            kq[j][i] = *(const float4*)(gK + (size_t)(k0s[j] + srow[i]) * RS + sc4[i] * 4);
            vq[j][i] = *(const float4*)(gV + (size_t)(k0s[j] + srow[i]) * RS + sc4[i] * 4);
        }

    // ---- all 4 tiles' masks, packed: bit (t*4+r) <-> k = k0s[j]+t*16+quad*4+r
    unsigned mbits[NTILE];
#pragma unroll
    for (int j = 0; j < NTILE; ++j) {
        unsigned bits = 0;
#pragma unroll
        for (int t = 0; t < 4; ++t) {
            int4 m = *(const int4*)(gM + k0s[j] + t * 16 + quad * 4);
            bits |= (m.x ? 1u : 0u) << (t * 4 + 0);
            bits |= (m.y ? 1u : 0u) << (t * 4 + 1);
            bits |= (m.z ? 1u : 0u) << (t * 4 + 2);
            bits |= (m.w ? 1u : 0u) << (t * 4 + 3);
        }
        mbits[j] = bits;
    }

    // ---- Q fragments, pre-scaled by 1/sqrt(D); B-operand of S^T = K Q^T
    bf16x8 qfrag[2];
#pragma unroll
    for (int c = 0; c < 2; ++c) {
        const float* src = gQ + (size_t)(qrow + ln) * RS + c * 32 + quad * 8;
        float4 f0 = *(const float4*)(src);
        float4 f1 = *(const float4*)(src + 4);
        bf16x8 t;
        t[0] = (__bf16)(f0.x * 0.125f); t[1] = (__bf16)(f0.y * 0.125f);
        t[2] = (__bf16)(f0.z * 0.125f); t[3] = (__bf16)(f0.w * 0.125f);
        t[4] = (__bf16)(f1.x * 0.125f); t[5] = (__bf16)(f1.y * 0.125f);
        t[6] = (__bf16)(f1.z * 0.125f); t[7] = (__bf16)(f1.w * 0.125f);
        qfrag[c] = t;
    }

    f32x4 o_acc[4];   // O^T C-layout: lane holds O[q=qrow+ln][d=nt*16+quad*4+r]
#pragma unroll
    for (int i = 0; i < 4; ++i) o_acc[i] = f32x4{0.f, 0.f, 0.f, 0.f};
    float l_sum = 0.f;

#pragma unroll
    for (int j = 0; j < NTILE; ++j) {
        const int bb = j & 1;
        const int k0 = k0s[j];

        // ---- store register tile j into LDS buffer bb ----
#pragma unroll
        for (int i = 0; i < 2; ++i) {
            float4 f = kq[j][i];
            bf16x4 kk;
            kk[0] = (__bf16)f.x; kk[1] = (__bf16)f.y;
            kk[2] = (__bf16)f.z; kk[3] = (__bf16)f.w;
            *(bf16x4*)&sK[bb][srow[i]][sc4[i] * 4] = kk;
            float4 g = vq[j][i];
            sVt[bb][sc4[i] * 4 + 0][srow[i]] = (__bf16)g.x;
            sVt[bb][sc4[i] * 4 + 1][srow[i]] = (__bf16)g.y;
            sVt[bb][sc4[i] * 4 + 2][srow[i]] = (__bf16)g.z;
            sVt[bb][sc4[i] * 4 + 3][srow[i]] = (__bf16)g.w;
        }
        __syncthreads();   // single barrier per tile (double-buffered K/V)

        // ---- S^T = K Q^T: C-layout row = k-sub = quad*4+r, col = q = ln ----
        f32x4 st[4];
#pragma unroll
        for (int t = 0; t < 4; ++t) {
            f32x4 acc = f32x4{0.f, 0.f, 0.f, 0.f};
#pragma unroll
            for (int ch = 0; ch < 2; ++ch) {
                bf16x8 kf = *(const bf16x8*)&sK[bb][t * 16 + ln][ch * 32 + quad * 8];
                acc = __builtin_amdgcn_mfma_f32_16x16x32_bf16(kf, qfrag[ch], acc, 0, 0, 0);
            }
            st[t] = acc;
        }

        // ---- fixed-shift softmax; P^T stored k-contiguous (one b64 per block) ----
        const int qg = qrow + ln;
#pragma unroll
        for (int t = 0; t < 4; ++t) {
            bf16x4 pt;
#pragma unroll
            for (int r = 0; r < 4; ++r) {
                int kg = k0 + t * 16 + quad * 4 + r;
                int dd = qg - kg; dd = dd < 0 ? -dd : dd;
                int d2 = LSEQ - dd; dd = d2 < dd ? d2 : dd;
                float mf = ((mbits[j] >> (t * 4 + r)) & 1u) ? EXP_NEG8 : 0.f;
                float p = __expf(st[t][r] - (float)dd) * mf;
                l_sum += p;
                pt[r] = (__bf16)p;
            }
            *(bf16x4*)&sPT[wave][ln][t * 16 + quad * 4] = pt;
        }

        // ---- O^T += V^T P^T ----
#pragma unroll
        for (int ch = 0; ch < 2; ++ch) {
            bf16x8 pb = *(const bf16x8*)&sPT[wave][ln][ch * 32 + quad * 8];
#pragma unroll
            for (int nt = 0; nt < 4; ++nt) {
                bf16x8 vf = *(const bf16x8*)&sVt[bb][nt * 16 + ln][ch * 32 + quad * 8];
                o_acc[nt] = __builtin_amdgcn_mfma_f32_16x16x32_bf16(vf, pb, o_acc[nt], 0, 0, 0);
            }
        }
        // no trailing barrier: next iter writes the other K/V buffer; its barrier orders reuse.
    }

    // ---- epilogue: reduce l across quads (2 shuffles), plain coalesced float4 stores ----
    float l = l_sum;
    l += __shfl_xor(l, 16, 64);
    l += __shfl_xor(l, 32, 64);
    const float inv = 1.f / l;

    float* dst = gO + (size_t)(qrow + ln) * RS + quad * 4;
#pragma unroll
    for (int nt = 0; nt < 4; ++nt) {
        float4 ov;
        ov.x = o_acc[nt][0] * inv;
        ov.y = o_acc[nt][1] * inv;
        ov.z = o_acc[nt][2] * inv;
        ov.w = o_acc[nt][3] * inv;
        *(float4*)(dst + nt * 16) = ov;
    }
}

extern "C" void kernel_launch(void* const* d_in, const int* in_sizes, int n_in,
                              void* d_out, int out_size, void* d_ws, size_t ws_size,
                              hipStream_t stream) {
    const float* Q  = (const float*)d_in[0];
    const float* K  = (const float*)d_in[1];
    const float* V  = (const float*)d_in[2];
    const int*   Mk = (const int*)d_in[3];
    float*       O  = (float*)d_out;

    dim3 grid(2 * NH * NQT);   // 512 blocks
    dim3 block(512);
    attn_kernel<<<grid, block, 0, stream>>>(Q, K, V, Mk, O);
}